// Round 1
// baseline (237.623 us; speedup 1.0000x reference)
//
#include <hip/hip_runtime.h>
#include <hip/hip_bf16.h>
#include <stdint.h>

typedef __bf16 bf16_t;
typedef __bf16 bf16x4 __attribute__((ext_vector_type(4)));
typedef __bf16 bf16x8 __attribute__((ext_vector_type(8)));
typedef float  f32x4  __attribute__((ext_vector_type(4)));

#define MFMA16(a,b,c) __builtin_amdgcn_mfma_f32_16x16x32_bf16((a),(b),(c),0,0,0)

static constexpr int DIM = 1024, HEADS = 16, HD = 64, NB = 2, NQ = 2048, NKK = 2048;
static constexpr int MROWS = NB * NQ; // 4096 token rows

// ---------------- f32 -> bf16 convert (vectorized) ----------------
__global__ void cvt_f32_bf16(const float* __restrict__ in, bf16_t* __restrict__ out, int n4) {
  int i = blockIdx.x * 256 + threadIdx.x;
  if (i >= n4) return;
  float4 v = reinterpret_cast<const float4*>(in)[i];
  bf16x4 o;
  o[0] = (bf16_t)v.x; o[1] = (bf16_t)v.y; o[2] = (bf16_t)v.z; o[3] = (bf16_t)v.w;
  *reinterpret_cast<bf16x4*>(out + (size_t)i * 4) = o;
}

// ---------------- LDS staging with chunk-XOR swizzle ----------------
// Tile: ROWS x 64 bf16 (128B/row = 8 x 16B chunks). LDS linear; the global
// SOURCE is pre-swizzled (chunk x fetches global chunk x^(r&7)) so reads can
// un-swizzle -> conflict-free-ish ds_read_b128 (2-way = free).
template<int ROWS>
__device__ __forceinline__ void stage_swz(const bf16_t* gbase, int gstride, bf16_t* lds, int tid) {
#pragma unroll
  for (int c = 0; c < ROWS / 32; ++c) {          // 256 chunks per iteration
    int p = c * 256 + tid;                        // 16B-chunk index
    int r = p >> 3, x = p & 7;
    const bf16_t* src = gbase + (size_t)r * gstride + ((x ^ (r & 7)) << 3);
    __builtin_amdgcn_global_load_lds(
        (const __attribute__((address_space(1))) void*)src,
        (__attribute__((address_space(3))) void*)(lds + (p << 3)),
        16, 0, 0);
  }
}

__device__ __forceinline__ bf16x8 lds_read8_swz(const bf16_t* lds, int row, int chunk) {
  int sc = chunk ^ (row & 7);
  return *reinterpret_cast<const bf16x8*>(lds + row * 64 + (sc << 3));
}

// ---------------- GEMM: C[M,N] = A(MxK) * Bt(NxK)^T ----------------
// MODE 0: bf16 row-major out. MODE 1: f32 row-major + bias. MODE 2: bf16 out
// scattered to per-head-transposed V layout (B,H,Dh,NK).
template<int MODE>
__global__ __launch_bounds__(256) void gemm_bt(const bf16_t* __restrict__ A,
                                               const bf16_t* __restrict__ Bt,
                                               void* __restrict__ Cout,
                                               const float* __restrict__ bias,
                                               int M, int N, int K) {
  __shared__ __align__(16) bf16_t As[128 * 64];
  __shared__ __align__(16) bf16_t Bs[128 * 64];
  const int tid = threadIdx.x;
  const int lane = tid & 63, wid = tid >> 6;
  const int l15 = lane & 15, lg = lane >> 4;
  const int wr = wid >> 1, wc = wid & 1;       // wave 64x64 sub-tile
  const int bn = blockIdx.x, bm = blockIdx.y;

  const bf16_t* Abase = A + (size_t)(bm * 128) * K;
  const bf16_t* Bbase = Bt + (size_t)(bn * 128) * K;

  f32x4 acc[4][4];
#pragma unroll
  for (int m = 0; m < 4; ++m)
#pragma unroll
    for (int n = 0; n < 4; ++n) acc[m][n] = (f32x4){0.f, 0.f, 0.f, 0.f};

  for (int k0 = 0; k0 < K; k0 += 64) {
    __syncthreads();
    stage_swz<128>(Abase + k0, K, As, tid);
    stage_swz<128>(Bbase + k0, K, Bs, tid);
    __syncthreads();
#pragma unroll
    for (int kk = 0; kk < 2; ++kk) {
      bf16x8 af[4], bfr[4];
#pragma unroll
      for (int m = 0; m < 4; ++m) af[m] = lds_read8_swz(As, wr * 64 + m * 16 + l15, kk * 4 + lg);
#pragma unroll
      for (int n = 0; n < 4; ++n) bfr[n] = lds_read8_swz(Bs, wc * 64 + n * 16 + l15, kk * 4 + lg);
#pragma unroll
      for (int m = 0; m < 4; ++m)
#pragma unroll
        for (int n = 0; n < 4; ++n)
          acc[m][n] = MFMA16(af[m], bfr[n], acc[m][n]);
    }
  }

  if (MODE == 2) {
    // V^T per head: Vt[((b*16+h)*64+d)*2048 + kv]; pack 4 consecutive kv (j).
#pragma unroll
    for (int m = 0; m < 4; ++m) {
      int row0 = bm * 128 + wr * 64 + m * 16 + lg * 4;
      int bb = row0 >> 11, kv = row0 & 2047;
#pragma unroll
      for (int n = 0; n < 4; ++n) {
        int col = bn * 128 + wc * 64 + n * 16 + l15;
        int hh = col >> 6, dd = col & 63;
        bf16x4 pk;
#pragma unroll
        for (int j = 0; j < 4; ++j) pk[j] = (bf16_t)acc[m][n][j];
        *reinterpret_cast<bf16x4*>(((bf16_t*)Cout) + (((size_t)((bb * 16 + hh) * 64 + dd)) << 11) + kv) = pk;
      }
    }
  } else {
#pragma unroll
    for (int m = 0; m < 4; ++m)
#pragma unroll
      for (int n = 0; n < 4; ++n)
#pragma unroll
        for (int j = 0; j < 4; ++j) {
          int row = bm * 128 + wr * 64 + m * 16 + lg * 4 + j;
          int col = bn * 128 + wc * 64 + n * 16 + l15;
          float v = acc[m][n][j];
          if (MODE == 0) ((bf16_t*)Cout)[(size_t)row * N + col] = (bf16_t)v;
          else           ((float*)Cout)[(size_t)row * N + col] = v + bias[col];
        }
  }
}

// ---------------- fused flash attention ----------------
// grid (NQ/64, HEADS, B); 4 waves x 16 q-rows. Q,K row-major per head slice;
// V pre-transposed (B,H,Dh,NK) so PV B-operand reads are contiguous.
__global__ __launch_bounds__(256) void attn_fused(const bf16_t* __restrict__ Qp,
                                                  const bf16_t* __restrict__ Kp,
                                                  const bf16_t* __restrict__ Vt,
                                                  bf16_t* __restrict__ Xa) {
  __shared__ __align__(16) bf16_t Qs[64 * 64];
  __shared__ __align__(16) bf16_t Ks[64 * 64];
  __shared__ __align__(16) bf16_t Vs[64 * 64];
  __shared__ __align__(16) bf16_t Ps[4][16 * 80];   // per-wave P, padded rows
  const int tid = threadIdx.x;
  const int lane = tid & 63, wid = tid >> 6;
  const int l15 = lane & 15, lg = lane >> 4;
  const int b = blockIdx.z, h = blockIdx.y, q0 = blockIdx.x * 64;

  const bf16_t* qbase = Qp + ((size_t)(b * NQ + q0)) * DIM + h * HD;
  const bf16_t* kbase = Kp + ((size_t)b * NKK) * DIM + h * HD;
  const bf16_t* vbase = Vt + ((size_t)((b * HEADS + h) * HD)) * NKK;

  stage_swz<64>(qbase, DIM, Qs, tid);
  __syncthreads();
  bf16x8 qf[2];
  qf[0] = lds_read8_swz(Qs, wid * 16 + l15, lg);
  qf[1] = lds_read8_swz(Qs, wid * 16 + l15, 4 + lg);

  float m_[4] = {-1e30f, -1e30f, -1e30f, -1e30f};
  float l_[4] = {0.f, 0.f, 0.f, 0.f};
  f32x4 o[4];
#pragma unroll
  for (int n = 0; n < 4; ++n) o[n] = (f32x4){0.f, 0.f, 0.f, 0.f};

  for (int kv0 = 0; kv0 < NKK; kv0 += 64) {
    __syncthreads();   // protect Ks/Vs (and Ps) from previous iteration readers
    stage_swz<64>(kbase + (size_t)kv0 * DIM, DIM, Ks, tid);
    stage_swz<64>(vbase + kv0, NKK, Vs, tid);
    __syncthreads();

    // S = Q K^T * scale  (D frag: row q=(lg*4+j), col k=l15 per 16-subtile)
    f32x4 s[4];
#pragma unroll
    for (int t = 0; t < 4; ++t) s[t] = (f32x4){0.f, 0.f, 0.f, 0.f};
#pragma unroll
    for (int t = 0; t < 4; ++t) {
      bf16x8 kf0 = lds_read8_swz(Ks, t * 16 + l15, lg);
      bf16x8 kf1 = lds_read8_swz(Ks, t * 16 + l15, 4 + lg);
      s[t] = MFMA16(qf[0], kf0, s[t]);
      s[t] = MFMA16(qf[1], kf1, s[t]);
    }
#pragma unroll
    for (int t = 0; t < 4; ++t) s[t] *= 0.125f;

    // online softmax (row = q, spread over 16 lanes l15 x 4 subtiles)
    float mn[4], alpha[4], rs[4];
#pragma unroll
    for (int j = 0; j < 4; ++j) {
      float rm = fmaxf(fmaxf(s[0][j], s[1][j]), fmaxf(s[2][j], s[3][j]));
      rm = fmaxf(rm, __shfl_xor(rm, 1));
      rm = fmaxf(rm, __shfl_xor(rm, 2));
      rm = fmaxf(rm, __shfl_xor(rm, 4));
      rm = fmaxf(rm, __shfl_xor(rm, 8));
      mn[j] = fmaxf(m_[j], rm);
      alpha[j] = __expf(m_[j] - mn[j]);
      m_[j] = mn[j];
      rs[j] = 0.f;
    }
#pragma unroll
    for (int t = 0; t < 4; ++t)
#pragma unroll
      for (int j = 0; j < 4; ++j) {
        float p = __expf(s[t][j] - mn[j]);
        s[t][j] = p;
        rs[j] += p;
      }
#pragma unroll
    for (int j = 0; j < 4; ++j) {
      rs[j] += __shfl_xor(rs[j], 1);
      rs[j] += __shfl_xor(rs[j], 2);
      rs[j] += __shfl_xor(rs[j], 4);
      rs[j] += __shfl_xor(rs[j], 8);
      l_[j] = l_[j] * alpha[j] + rs[j];
    }
#pragma unroll
    for (int n = 0; n < 4; ++n)
#pragma unroll
      for (int j = 0; j < 4; ++j) o[n][j] *= alpha[j];

    // P -> LDS (D-layout) then re-read as A-operand layout
    bf16_t* Pw = &Ps[wid][0];
#pragma unroll
    for (int t = 0; t < 4; ++t)
#pragma unroll
      for (int j = 0; j < 4; ++j)
        Pw[(lg * 4 + j) * 80 + t * 16 + l15] = (bf16_t)s[t][j];
    asm volatile("s_waitcnt lgkmcnt(0)" ::: "memory");
    bf16x8 pf0 = *reinterpret_cast<const bf16x8*>(Pw + l15 * 80 + lg * 8);
    bf16x8 pf1 = *reinterpret_cast<const bf16x8*>(Pw + l15 * 80 + 32 + lg * 8);

    // O += P * V   (B-operand rows = d in Vs[d][kv])
#pragma unroll
    for (int n = 0; n < 4; ++n) {
      bf16x8 vf0 = lds_read8_swz(Vs, n * 16 + l15, lg);
      bf16x8 vf1 = lds_read8_swz(Vs, n * 16 + l15, 4 + lg);
      o[n] = MFMA16(pf0, vf0, o[n]);
      o[n] = MFMA16(pf1, vf1, o[n]);
    }
  }

  // epilogue: normalize and store bf16
#pragma unroll
  for (int j = 0; j < 4; ++j) {
    float inv = 1.f / l_[j];
    int q = q0 + wid * 16 + lg * 4 + j;
#pragma unroll
    for (int n = 0; n < 4; ++n) {
      int d = h * HD + n * 16 + l15;
      Xa[((size_t)(b * NQ + q)) * DIM + d] = (bf16_t)(o[n][j] * inv);
    }
  }
}

// ---------------- launcher ----------------
extern "C" void kernel_launch(void* const* d_in, const int* in_sizes, int n_in,
                              void* d_out, int out_size, void* d_ws, size_t ws_size,
                              hipStream_t stream) {
  (void)in_sizes; (void)n_in; (void)out_size; (void)ws_size;
  const float* q  = (const float*)d_in[0];
  const float* k  = (const float*)d_in[1];
  const float* v  = (const float*)d_in[2];
  const float* Wq = (const float*)d_in[5];
  const float* Wk = (const float*)d_in[6];
  const float* Wv = (const float*)d_in[7];
  const float* Wo = (const float*)d_in[8];
  const float* bo = (const float*)d_in[9];
  float* out = (float*)d_out;

  bf16_t* ws = (bf16_t*)d_ws;
  const size_t SZ_IN = (size_t)MROWS * DIM;  // 4M elems
  const size_t SZ_W  = (size_t)DIM * DIM;    // 1M elems
  bf16_t* qb  = ws;
  bf16_t* kb  = qb  + SZ_IN;
  bf16_t* vb  = kb  + SZ_IN;
  bf16_t* wqb = vb  + SZ_IN;
  bf16_t* wkb = wqb + SZ_W;
  bf16_t* wvb = wkb + SZ_W;
  bf16_t* wob = wvb + SZ_W;
  bf16_t* Qp  = wob + SZ_W;
  bf16_t* Kp  = Qp  + SZ_IN;
  bf16_t* Vtp = Kp  + SZ_IN;
  bf16_t* Xa  = qb;  // alias: qb dead after Q projection (stream-ordered)

  cvt_f32_bf16<<<dim3((unsigned)(SZ_IN / 1024)), 256, 0, stream>>>(q, qb, (int)(SZ_IN / 4));
  cvt_f32_bf16<<<dim3((unsigned)(SZ_IN / 1024)), 256, 0, stream>>>(k, kb, (int)(SZ_IN / 4));
  cvt_f32_bf16<<<dim3((unsigned)(SZ_IN / 1024)), 256, 0, stream>>>(v, vb, (int)(SZ_IN / 4));
  cvt_f32_bf16<<<dim3((unsigned)(SZ_W / 1024)), 256, 0, stream>>>(Wq, wqb, (int)(SZ_W / 4));
  cvt_f32_bf16<<<dim3((unsigned)(SZ_W / 1024)), 256, 0, stream>>>(Wk, wkb, (int)(SZ_W / 4));
  cvt_f32_bf16<<<dim3((unsigned)(SZ_W / 1024)), 256, 0, stream>>>(Wv, wvb, (int)(SZ_W / 4));
  cvt_f32_bf16<<<dim3((unsigned)(SZ_W / 1024)), 256, 0, stream>>>(Wo, wob, (int)(SZ_W / 4));

  dim3 gg(DIM / 128, MROWS / 128);  // (8, 32)
  gemm_bt<0><<<gg, 256, 0, stream>>>(qb, wqb, (void*)Qp, nullptr, MROWS, DIM, DIM);
  gemm_bt<0><<<gg, 256, 0, stream>>>(kb, wkb, (void*)Kp, nullptr, MROWS, DIM, DIM);
  gemm_bt<2><<<gg, 256, 0, stream>>>(vb, wvb, (void*)Vtp, nullptr, MROWS, DIM, DIM);

  attn_fused<<<dim3(NQ / 64, HEADS, NB), 256, 0, stream>>>(Qp, Kp, Vtp, Xa);

  gemm_bt<1><<<gg, 256, 0, stream>>>(Xa, wob, (void*)out, bo, MROWS, DIM, DIM);
}